// Round 11
// baseline (45.965 us; speedup 1.0000x reference)
//
#include <hip/hip_runtime.h>
#include <hip/hip_fp16.h>

// NormalizingFlow: 4 layers of monotonic linear-rational splines (pyro-style),
// B=262144 rows, D=64 dims, K=8 bins.
//
// Each spline sub-piece (bin x lambda-half) is a Mobius map f(x)=(Ax+B)/(Cx+D);
// Mobius maps compose -> piecewise-Mobius with <= 61 pieces per dim.
// Precompute: det-normalized (det=1), LEFT-KNOT-CENTERED matrices stored fp16
// (4 halves / piece). Main: 2-level search (coarse regs + binary fine w/ lf
// tracking), one ds_read_b64 coeff gather, Mobius on t=xc-lf;
// lad = -2 ln|den|; DPP wave reduce.
// LDS = 16KB knots + 30.5KB fp16 coeffs = 47616B; 512-thread blocks so
// 3 blocks/CU (24 waves) can co-schedule — the occupancy lever.

#define BATCH 262144
#define DIM   64
#define NLAY  4
#define NK    8

// float offsets in d_ws (units: floats from base)
#define OFF_KN0 0       // [8][64][4] fine knots bnd[8c+0..3] (slot0 = -3.0)
#define OFF_KN1 2048    // [8][64][4] fine knots bnd[8c+4..7]
#define OFF_CRS 4096    // [7][64] coarse knots bnd[8],bnd[16],...,bnd[56]
#define OFF_CFH 4544    // [61][64] uint2 = {half2(A,B), half2(C,D)} centered

// Fused precompute: one block per dim d (64 blocks x 64 threads).
__global__ void nf_pre(const float* __restrict__ uw, const float* __restrict__ uh,
                       const float* __restrict__ ud, const float* __restrict__ ul,
                       float* __restrict__ F) {
  __shared__ double Lb[NLAY][17], Ly[NLAY][17], LM[NLAY][16][4], Ld[NLAY][16];
  __shared__ double sx[64], Fb[65];
  int d = blockIdx.x;
  int t = threadIdx.x;

  if (t < 32) {
    int l = t >> 3, k = t & 7;
    const float* pw  = uw + (l*DIM + d)*NK;
    const float* ph  = uh + (l*DIM + d)*NK;
    const float* pdv = ud + (l*DIM + d)*(NK-1);
    const float* pl  = ul + (l*DIM + d)*NK;

    // widths softmax (serial-order rounding preserved)
    float ev[NK];
    float mw = pw[0];
    for (int j = 1; j < NK; ++j) mw = fmaxf(mw, pw[j]);
    float sw = 0.f;
    for (int j = 0; j < NK; ++j) { ev[j] = expf(pw[j] - mw); sw += ev[j]; }
    float invw = 1.f / sw;
    float cwe = 0.f, cwi = 0.f;
    for (int j = 0; j <= k; ++j) {
      float vj = 1e-3f + (1.f - 1e-3f * (float)NK) * (ev[j] * invw);
      cwe = cwi; cwi += vj;
    }
    float kwL = (k == 0) ? -3.f : 6.f * cwe - 3.f;
    float kwR = (k == 7) ?  3.f : 6.f * cwi - 3.f;
    float wwk = kwR - kwL;

    // heights softmax
    float mh = ph[0];
    for (int j = 1; j < NK; ++j) mh = fmaxf(mh, ph[j]);
    float sh = 0.f;
    for (int j = 0; j < NK; ++j) { ev[j] = expf(ph[j] - mh); sh += ev[j]; }
    float invh = 1.f / sh;
    float che = 0.f, chi = 0.f;
    for (int j = 0; j <= k; ++j) {
      float vj = 1e-3f + (1.f - 1e-3f * (float)NK) * (ev[j] * invh);
      che = chi; chi += vj;
    }
    float khL = (k == 0) ? -3.f : 6.f * che - 3.f;
    float khR = (k == 7) ?  3.f : 6.f * chi - 3.f;
    float hhk = khR - khL;

    // derivatives at both ends of bin k; lambda
    float dvk, dvk1;
    if (k == 0) dvk = 1.f;
    else { float u = pdv[k-1]; dvk  = 1e-3f + (fmaxf(u,0.f) + log1pf(expf(-fabsf(u)))); }
    if (k == 7) dvk1 = 1.f;
    else { float u = pdv[k];   dvk1 = 1e-3f + (fmaxf(u,0.f) + log1pf(expf(-fabsf(u)))); }
    float sg = 1.f / (1.f + expf(-pl[k]));
    float lmk = 0.95f * sg + 0.025f;

    float delta = hhk / wwk;
    float wbf = sqrtf(dvk / dvk1);
    float wcf = (lmk*dvk + (1.f-lmk)*wbf*dvk1) / delta;
    float yaf = khL, ybf = hhk + khL;
    float ycf = ((1.f-lmk)*yaf + lmk*wbf*ybf) / ((1.f-lmk) + lmk*wbf);

    if (k == 0) {
      Lb[l][0] = -3.0; Lb[l][16] = 3.0;
      Ly[l][0] = -3.0; Ly[l][16] = 3.0;
    }
    if (k) Lb[l][2*k] = (double)(kwL + 1.0e-6f);   // bin boundary (fp32 +EPS)
    Lb[l][2*k+1] = (double)kwL + (double)lmk*(double)wwk;  // theta==lambda
    Ly[l][2*k]   = (double)yaf;
    Ly[l][2*k+1] = (double)ycf;

    double icw = (double)kwL, iw = (double)wwk, il = (double)lmk;
    double wb = wbf, wc = wcf, ya = yaf, yb = ybf, yc = ycf;
    double n0 = ya*il, n1 = wc*yc - ya, d0 = il, d1 = wc - 1.0;
    double A = n1, Bv = n0*iw - n1*icw, C = d1, Dv = d0*iw - d1*icw;
    LM[l][2*k][0]=A; LM[l][2*k][1]=Bv; LM[l][2*k][2]=C; LM[l][2*k][3]=Dv;
    Ld[l][2*k] = log2(A*Dv - Bv*C);
    n0 = wc*yc - il*wb*yb; n1 = wb*yb - wc*yc; d0 = wc - il*wb; d1 = wb - wc;
    A = n1; Bv = n0*iw - n1*icw; C = d1; Dv = d0*iw - d1*icw;
    LM[l][2*k+1][0]=A; LM[l][2*k+1][1]=Bv; LM[l][2*k+1][2]=C; LM[l][2*k+1][3]=Dv;
    Ld[l][2*k+1] = log2(A*Dv - Bv*C);
  }
  __syncthreads();

  if (t < 60) {
    int lp  = t / 15;
    int mth = t % 15 + 1;
    double x = Lb[lp][mth];
    for (int q = lp - 1; q >= 0; --q) {
      int j = 0;
      for (int k = 1; k <= 15; ++k) j += (x >= Ly[q][k]) ? 1 : 0;
      const double* M = LM[q][j];
      x = (M[3]*x - M[1]) / (M[0] - M[2]*x);  // Mobius inverse
    }
    sx[t] = x;
  }
  __syncthreads();
  if (t < 60) {
    double x = sx[t];
    int r = 0;
    for (int s2 = 0; s2 < 60; ++s2) {
      double o = sx[s2];
      r += (o < x || (o == x && s2 < t)) ? 1 : 0;
    }
    Fb[r+1] = x;
  }
  if (t == 0)  Fb[0] = -3.0;
  if (t >= 60) Fb[t+1] = 3.0;   // Fb[61..64] geometry pads
  __syncthreads();

  // fp32 search tables
  {
    int j = t;
    float bf;
    if (j == 0)       bf = -3.0f;
    else if (j <= 60) bf = (float)Fb[j];
    else              bf = 1e30f;         // pads: never counted
    int cw = j >> 3, r8 = j & 7;
    if (r8 < 4) F[OFF_KN0 + (cw*DIM + d)*4 + r8]     = bf;
    else        F[OFF_KN1 + (cw*DIM + d)*4 + (r8-4)] = bf;
    if (j >= 8 && (j & 7) == 0 && j <= 56) F[OFF_CRS + (j/8 - 1)*DIM + d] = bf;
  }

  // per-piece composed coefficients: center at LEFT knot (fp32-rounded, equals
  // the search-table value), det -> 1, pack fp16.
  if (t < 61) {
    int p = t;
    double bl = Fb[p], br = Fb[p+1];
    float xmf = (float)(0.5*(bl+br));
    xmf = fminf(fmaxf(xmf, -3.f), 3.f);
    double y = (double)xmf;
    double A=1.0, Bv=0.0, C=0.0, Dv=1.0, ld2 = 0.0;
    for (int q = 0; q < NLAY; ++q) {
      int j = 0;
      for (int k = 1; k <= 15; ++k) j += (y >= Lb[q][k]) ? 1 : 0;
      const double* M = LM[q][j];
      ld2 += Ld[q][j];
      double A2 = M[0]*A + M[1]*C, B2 = M[0]*Bv + M[1]*Dv;
      double C2 = M[2]*A + M[3]*C, D2 = M[2]*Bv + M[3]*Dv;
      y = (M[0]*y + M[1]) / (M[2]*y + M[3]);
      A=A2; Bv=B2; C=C2; Dv=D2;
    }
    float leftf = (p == 0) ? -3.0f : (float)bl;   // == search-table lf
    double xl = (double)leftf;
    double Bp = A*xl + Bv, Dp = C*xl + Dv;        // recenter (unimodular)
    double sinv = exp2(-0.5 * ld2);               // det -> 1
    float Af = (float)(A*sinv),  Bf = (float)(Bp*sinv);
    float Cf = (float)(C*sinv),  Df = (float)(Dp*sinv);
    __half2 hab = __floats2half2_rn(Af, Bf);
    __half2 hcd = __floats2half2_rn(Cf, Df);
    uint2 cw;
    cw.x = __builtin_bit_cast(unsigned int, hab);
    cw.y = __builtin_bit_cast(unsigned int, hcd);
    *(uint2*)(F + OFF_CFH + (size_t)(p*DIM + d)*2) = cw;
  }
}

template <int CTRL>
__device__ __forceinline__ float dpp_add(float x) {
  // bound_ctrl=true: invalid source lanes read 0 -> folds to one v_add_f32_dpp
  int yi = __builtin_amdgcn_update_dpp(0, __float_as_int(x), CTRL, 0xF, 0xF, true);
  return x + __int_as_float(yi);
}
// wave64 sum -> lane 63 (rocPRIM gfx9 sequence)
__device__ __forceinline__ float wave_sum63(float x) {
  x = dpp_add<0x111>(x);  // row_shr:1
  x = dpp_add<0x112>(x);  // row_shr:2
  x = dpp_add<0x114>(x);  // row_shr:4
  x = dpp_add<0x118>(x);  // row_shr:8
  x = dpp_add<0x142>(x);  // row_bcast:15
  x = dpp_add<0x143>(x);  // row_bcast:31
  return x;
}

// Main: lane = dim; wave owns 32 rows as 16 units of 2, software-pipelined
// (R1 coarse+knot-issue / R2 math / R3 binary-fine+coeff-issue), 3 groups x 5
// units + epilogue, group-local pointers. 512-thread blocks, 47.6KB LDS ->
// 3 blocks/CU (24 waves) can co-schedule.
__global__ __launch_bounds__(512, 6) void nf_main(const float* __restrict__ X,
                                                  const float* __restrict__ F,
                                                  float* __restrict__ OUT,
                                                  float* __restrict__ LDo) {
  __shared__ float smem[11904];   // [0,4096): knots fp32; [4096,11904): fp16 coeffs
  int t = threadIdx.x;
  {
    float4* dst = (float4*)smem;
    const float4* kt = (const float4*)(F + OFF_KN0);
    dst[t] = kt[t]; dst[t + 512] = kt[t + 512];
    uint2* dh = (uint2*)(smem + 4096);
    const uint2* ch = (const uint2*)(F + OFF_CFH);
    for (int i = t; i < 3904; i += 512) dh[i] = ch[i];
  }
  int d = t & 63;
  float k1 = F[OFF_CRS + 0*DIM + d];
  float k2 = F[OFF_CRS + 1*DIM + d];
  float k3 = F[OFF_CRS + 2*DIM + d];
  float k4 = F[OFF_CRS + 3*DIM + d];
  float k5 = F[OFF_CRS + 4*DIM + d];
  float k6 = F[OFF_CRS + 5*DIM + d];
  float k7 = F[OFF_CRS + 6*DIM + d];
  __syncthreads();
  const float4* skv = (const float4*)smem;
  const uint2*  scf = (const uint2*)(smem + 4096);

  int gw = blockIdx.x * 8 + (t >> 6);           // 0..8191; wave owns 32 rows
  const float* Xp = X   + (size_t)gw*32*DIM + d;
  float*       Op = OUT + (size_t)gw*32*DIM + d;
  float*       Lp = LDo + (size_t)gw*32;

#define COARSE(xc) ((xc>=k1)+(xc>=k2)+(xc>=k3)+(xc>=k4)+(xc>=k5)+(xc>=k6)+(xc>=k7))
  // binary fine search tracking left knot; returns p and lf
#define FINEB(xc, cc, f0, f1, P, LF)                                          \
  {                                                                           \
    bool b4 = (xc) >= f1.x;                                                   \
    float c2v = b4 ? f1.z : f0.z;                                             \
    bool b2 = (xc) >= c2v;                                                    \
    float c1a = b4 ? f1.y : f0.y;                                             \
    float c1b = b4 ? f1.w : f0.w;                                             \
    float c1v = b2 ? c1b : c1a;                                               \
    bool b1 = (xc) >= c1v;                                                    \
    float lf_ = f0.x;                                                         \
    lf_ = b4 ? f1.x : lf_;                                                    \
    lf_ = b2 ? c2v  : lf_;                                                    \
    lf_ = b1 ? c1v  : lf_;                                                    \
    P = ((cc)<<3) + (((int)b4)<<2) + (((int)b2)<<1) + (int)b1;                \
    LF = lf_;                                                                 \
  }

  // ---- prologue: full search of unit 0; load x of unit 1 ----
  float xA0 = Xp[0], xA1 = Xp[64];
  float xB0 = Xp[128], xB1 = Xp[192];
  float xcA0 = __builtin_amdgcn_fmed3f(xA0, -3.f, 3.f);
  float xcA1 = __builtin_amdgcn_fmed3f(xA1, -3.f, 3.f);
  float lfA0, lfA1;
  uint2 cwA0, cwA1;
  {
    int c0 = COARSE(xcA0), c1 = COARSE(xcA1);
    float4 f00 = skv[(c0<<6)+d], f01 = skv[512+(c0<<6)+d];
    float4 f10 = skv[(c1<<6)+d], f11 = skv[512+(c1<<6)+d];
    int p0, p1;
    FINEB(xcA0, c0, f00, f01, p0, lfA0)
    FINEB(xcA1, c1, f10, f11, p1, lfA1)
    cwA0 = scf[(p0<<6)+d];
    cwA1 = scf[(p1<<6)+d];
  }

  for (int g = 0; g < 3; ++g) {
#pragma unroll
    for (int u = 0; u < 5; ++u) {
      // ---- R1: coarse(next unit), issue fine reads; prefetch x(unit+2) ----
      float xcB0 = __builtin_amdgcn_fmed3f(xB0, -3.f, 3.f);
      float xcB1 = __builtin_amdgcn_fmed3f(xB1, -3.f, 3.f);
      int cB0 = COARSE(xcB0), cB1 = COARSE(xcB1);
      float4 f00 = skv[(cB0<<6)+d], f01 = skv[512+(cB0<<6)+d];
      float4 f10 = skv[(cB1<<6)+d], f11 = skv[512+(cB1<<6)+d];
      int lo = (u == 4) ? ((g == 2) ? 5 : 6) : (u + 2);   // group-local prefetch
      float xF0 = Xp[lo*128], xF1 = Xp[lo*128 + 64];
      __builtin_amdgcn_sched_barrier(0);
      // ---- R2: math(current unit) using cwA (read last iteration) ----
      float2 ab0 = __half22float2(__builtin_bit_cast(__half2, cwA0.x));
      float2 cd0 = __half22float2(__builtin_bit_cast(__half2, cwA0.y));
      float2 ab1 = __half22float2(__builtin_bit_cast(__half2, cwA1.x));
      float2 cd1 = __half22float2(__builtin_bit_cast(__half2, cwA1.y));
      float t0 = xcA0 - lfA0;
      float num0 = fmaf(ab0.x, t0, ab0.y);
      float den0 = fmaf(cd0.x, t0, cd0.y);
      float o0 = (xA0 == xcA0) ? __fdividef(num0, den0) : xA0;
      float l0 = __log2f(fabsf(den0));
      float t1 = xcA1 - lfA1;
      float num1 = fmaf(ab1.x, t1, ab1.y);
      float den1 = fmaf(cd1.x, t1, cd1.y);
      float o1 = (xA1 == xcA1) ? __fdividef(num1, den1) : xA1;
      float l1 = __log2f(fabsf(den1));
      Op[u*128] = o0; Op[u*128 + 64] = o1;
      float s0 = wave_sum63(l0);
      float s1 = wave_sum63(l1);
      if (d == 63) {
        float2 v;
        v.x = s0 * -1.3862943611198906f;   // -2*ln2 folded once per row
        v.y = s1 * -1.3862943611198906f;
        *(float2*)(Lp + 2*u) = v;
      }
      __builtin_amdgcn_sched_barrier(0);
      // ---- R3: binary fine-search(next unit) + issue coeff reads ----
      int p0, p1;
      float lfN0, lfN1;
      FINEB(xcB0, cB0, f00, f01, p0, lfN0)
      FINEB(xcB1, cB1, f10, f11, p1, lfN1)
      cwA0 = scf[(p0<<6)+d];
      cwA1 = scf[(p1<<6)+d];
      xA0 = xB0; xA1 = xB1; xcA0 = xcB0; xcA1 = xcB1;
      lfA0 = lfN0; lfA1 = lfN1;
      xB0 = xF0; xB1 = xF1;
    }
    Xp += 640; Op += 640; Lp += 10;
  }
  // ---- epilogue: math(unit 15); Op/Lp now point at its slots ----
  {
    float2 ab0 = __half22float2(__builtin_bit_cast(__half2, cwA0.x));
    float2 cd0 = __half22float2(__builtin_bit_cast(__half2, cwA0.y));
    float2 ab1 = __half22float2(__builtin_bit_cast(__half2, cwA1.x));
    float2 cd1 = __half22float2(__builtin_bit_cast(__half2, cwA1.y));
    float t0 = xcA0 - lfA0;
    float num0 = fmaf(ab0.x, t0, ab0.y);
    float den0 = fmaf(cd0.x, t0, cd0.y);
    float o0 = (xA0 == xcA0) ? __fdividef(num0, den0) : xA0;
    float l0 = __log2f(fabsf(den0));
    float t1 = xcA1 - lfA1;
    float num1 = fmaf(ab1.x, t1, ab1.y);
    float den1 = fmaf(cd1.x, t1, cd1.y);
    float o1 = (xA1 == xcA1) ? __fdividef(num1, den1) : xA1;
    float l1 = __log2f(fabsf(den1));
    Op[0] = o0; Op[64] = o1;
    float s0 = wave_sum63(l0);
    float s1 = wave_sum63(l1);
    if (d == 63) {
      float2 v;
      v.x = s0 * -1.3862943611198906f;
      v.y = s1 * -1.3862943611198906f;
      *(float2*)Lp = v;
    }
  }
#undef COARSE
#undef FINEB
}

extern "C" void kernel_launch(void* const* d_in, const int* in_sizes, int n_in,
                              void* d_out, int out_size, void* d_ws, size_t ws_size,
                              hipStream_t stream) {
  const float* x  = (const float*)d_in[0];
  const float* uw = (const float*)d_in[1];
  const float* uh = (const float*)d_in[2];
  const float* ud = (const float*)d_in[3];
  const float* ul = (const float*)d_in[4];
  float* out = (float*)d_out;
  float* F = (float*)d_ws;
  nf_pre<<<DIM, 64, 0, stream>>>(uw, uh, ud, ul, F);
  nf_main<<<1024, 512, 0, stream>>>(x, F, out, out + (size_t)BATCH*DIM);
}